// Round 2
// baseline (1850.865 us; speedup 1.0000x reference)
//
#include <hip/hip_runtime.h>

#define DEVINL __device__ __forceinline__

constexpr int PADF = 36;   // LDS row stride in floats (144B: 16B-aligned, breaks 32-bank alias)

DEVINL float lrelu1(float v)    { return v > 0.f ? v : 0.2f * v; }
DEVINL float invlrelu1(float v) { return v > 0.f ? v : 5.0f * v; }

// acc[32] += hrow(32 floats, own LDS row) @ wg[32][32] (global, wave-uniform -> s_load)
// kq outer (unroll 1, small code), 128 FMAs per h-read; h prefetched one iter ahead.
DEVINL void gemm_block(const float* __restrict__ wg, const float* hrow, float acc[32])
{
    float4 h = *(const float4*)(hrow);
#pragma unroll 1
    for (int kq = 0; kq < 8; ++kq) {
        float4 hn = *(const float4*)(hrow + ((kq + 1) & 7) * 4);   // prefetch next quad
#pragma unroll
        for (int i = 0; i < 4; ++i) {
            float hv = ((const float*)&h)[i];
            const float* wr = wg + (kq * 4 + i) * 32;
#pragma unroll
            for (int j = 0; j < 32; j += 4) {
                float4 w = *(const float4*)(wr + j);
                acc[j + 0] = fmaf(hv, w.x, acc[j + 0]);
                acc[j + 1] = fmaf(hv, w.y, acc[j + 1]);
                acc[j + 2] = fmaf(hv, w.z, acc[j + 2]);
                acc[j + 3] = fmaf(hv, w.w, acc[j + 3]);
            }
        }
        h = hn;
    }
}

// staging split (T14): issue global loads early ... ds_write late
DEVINL void stage_load(const float* __restrict__ src, float4 stg[8],
                       int base, int se, int sq, int limit)
{
#pragma unroll
    for (int p = 0; p < 8; ++p) {
        int m = base + p * 32 + se; if (m >= limit) m = limit - 1;
        stg[p] = *(const float4*)(src + (size_t)m * 32 + sq * 4);
    }
}

DEVINL void stage_write(const float4 stg[8], float* __restrict__ hs, int se, int sq)
{
#pragma unroll
    for (int p = 0; p < 8; ++p)
        *(float4*)&hs[(p * 32 + se) * PADF + sq * 4] = stg[p];
}

// ---------------- CSR build ----------------
__global__ __launch_bounds__(256)
void hist_kernel(const int* __restrict__ rowi, int* __restrict__ deg, int E)
{
    int e = blockIdx.x * 256 + threadIdx.x;
    if (e < E) atomicAdd(&deg[rowi[e]], 1);
}

__global__ __launch_bounds__(256)
void scan_kernel(const int* __restrict__ deg, int* __restrict__ off,
                 int* __restrict__ cursor, int N, int E)
{
    __shared__ int part[256];
    __shared__ int psum[256];
    const int t = threadIdx.x;
    const int per = (N + 255) / 256;
    const int b0 = t * per;
    int s = 0;
    for (int i = 0; i < per; ++i) { int idx = b0 + i; if (idx < N) s += deg[idx]; }
    part[t] = s;
    __syncthreads();
    if (t == 0) { int run = 0; for (int i = 0; i < 256; ++i) { psum[i] = run; run += part[i]; } }
    __syncthreads();
    int run = psum[t];
    for (int i = 0; i < per; ++i) {
        int idx = b0 + i;
        if (idx < N) { off[idx] = run; cursor[idx] = run; run += deg[idx]; }
    }
    if (t == 0) off[N] = E;
}

__global__ __launch_bounds__(256)
void place_kernel(const int* __restrict__ rowi, int* __restrict__ cursor,
                  int* __restrict__ perm, int E)
{
    int e = blockIdx.x * 256 + threadIdx.x;
    if (e < E) {
        int r = rowi[e];
        int p = atomicAdd(&cursor[r], 1);
        perm[p] = e;
    }
}

// ---------------- per-node precompute: Pr = x@w1[0:32] + b1, Pc = x@w1[32:64] ----------------
__global__ __launch_bounds__(256, 4)
void pre_kernel(const float* __restrict__ x, const float* __restrict__ w1,
                const float* __restrict__ b1,
                float* __restrict__ Pr, float* __restrict__ Pc, int N)
{
    __shared__ float hs[256 * PADF];
    const int tid = threadIdx.x;
    const int base = blockIdx.x * 256;
    const int se = tid >> 3, sq = tid & 7;
    const float* hrow = hs + tid * PADF;

    float4 stg[8];
    stage_load(x, stg, base, se, sq, N);
    stage_write(stg, hs, se, sq);
    __syncthreads();

    const int n = base + tid;
    float acc[32];
#pragma unroll
    for (int j = 0; j < 32; ++j) acc[j] = b1[j];
    gemm_block(w1, hrow, acc);
    if (n < N) {
#pragma unroll
        for (int j = 0; j < 32; j += 4)
            *(float4*)(Pr + (size_t)n * 32 + j) = make_float4(acc[j], acc[j+1], acc[j+2], acc[j+3]);
    }
#pragma unroll
    for (int j = 0; j < 32; ++j) acc[j] = 0.f;
    gemm_block(w1 + 1024, hrow, acc);
    if (n < N) {
#pragma unroll
        for (int j = 0; j < 32; j += 4)
            *(float4*)(Pc + (size_t)n * 32 + j) = make_float4(acc[j], acc[j+1], acc[j+2], acc[j+3]);
    }
}

// ---------------- edge conv ----------------
// acc = Pr[row] + Pc[col] (+ staged edge-feature chunks @ w1e) ; relu ; @w2+b2 ; lrelu
// FUSE: additionally run the 3-layer edge MLP in the same pass
template<int NCHUNK, bool FUSE>
__global__ __launch_bounds__(256, 4)
void conv_kernel(const float* __restrict__ Pr, const float* __restrict__ Pc,
                 const int* __restrict__ rowi, const int* __restrict__ coli,
                 const float* __restrict__ f0, const float* __restrict__ f1,
                 const float* __restrict__ f2,
                 const float* __restrict__ w1e,
                 const float* __restrict__ w2g, const float* __restrict__ b2g,
                 float* __restrict__ eout,
                 const float* __restrict__ mw1, const float* __restrict__ mb1,
                 const float* __restrict__ mw2, const float* __restrict__ mb2,
                 const float* __restrict__ mw3, const float* __restrict__ mb3,
                 float* __restrict__ mout,
                 int E)
{
    __shared__ float hs[256 * PADF];
    const int tid = threadIdx.x;
    const int base = blockIdx.x * 256;
    const int se = tid >> 3, sq = tid & 7;
    float* hrow = hs + tid * PADF;

    // chunk-0 staging loads + Pr/Pc gathers all in flight together
    float4 stg[8];
    stage_load(f0, stg, base, se, sq, E);

    const int e = base + tid;
    const int ee = e < E ? e : E - 1;
    const int r = rowi[ee], c = coli[ee];
    const float* pr = Pr + (size_t)r * 32;
    const float* pc = Pc + (size_t)c * 32;
    float acc[32];
#pragma unroll
    for (int q = 0; q < 8; ++q) {
        float4 ga = *(const float4*)(pr + q * 4);
        float4 gb = *(const float4*)(pc + q * 4);
        acc[q * 4 + 0] = ga.x + gb.x;
        acc[q * 4 + 1] = ga.y + gb.y;
        acc[q * 4 + 2] = ga.z + gb.z;
        acc[q * 4 + 3] = ga.w + gb.w;
    }
    stage_write(stg, hs, se, sq);
    __syncthreads();

#pragma unroll
    for (int cch = 0; cch < NCHUNK; ++cch) {
        if (cch + 1 < NCHUNK) {
            const float* src = (cch == 0) ? f1 : f2;
            stage_load(src, stg, base, se, sq, E);      // issue early: hides under gemm
        }
        gemm_block(w1e + cch * 1024, hrow, acc);
        if (cch + 1 < NCHUNK) {
            __syncthreads();                            // everyone's hrow reads done
            stage_write(stg, hs, se, sq);
            __syncthreads();
        }
    }

    // relu -> own LDS row (no barrier: only own-row access from here on)
#pragma unroll
    for (int j = 0; j < 32; j += 4) {
        float4 v;
        v.x = fmaxf(acc[j],     0.f); v.y = fmaxf(acc[j + 1], 0.f);
        v.z = fmaxf(acc[j + 2], 0.f); v.w = fmaxf(acc[j + 3], 0.f);
        *(float4*)&hrow[j] = v;
    }
    float acc2[32];
#pragma unroll
    for (int j = 0; j < 32; ++j) acc2[j] = b2g[j];
    gemm_block(w2g, hrow, acc2);

    if constexpr (!FUSE) {
        if (e < E) {
#pragma unroll
            for (int j = 0; j < 32; j += 4) {
                float4 v;
                v.x = lrelu1(acc2[j]);     v.y = lrelu1(acc2[j + 1]);
                v.z = lrelu1(acc2[j + 2]); v.w = lrelu1(acc2[j + 3]);
                *(float4*)(eout + (size_t)e * 32 + j) = v;
            }
        }
    } else {
        // e3 = lrelu(acc2) -> scratch (for scatter-mean) + own row (MLP input)
#pragma unroll
        for (int j = 0; j < 32; j += 4) {
            float4 v;
            v.x = lrelu1(acc2[j]);     v.y = lrelu1(acc2[j + 1]);
            v.z = lrelu1(acc2[j + 2]); v.w = lrelu1(acc2[j + 3]);
            *(float4*)&hrow[j] = v;
            if (e < E) *(float4*)(eout + (size_t)e * 32 + j) = v;
        }
        float acc3[32];
#pragma unroll
        for (int j = 0; j < 32; ++j) acc3[j] = mb1[j];
        gemm_block(mw1, hrow, acc3);
#pragma unroll
        for (int j = 0; j < 32; j += 4) {
            float4 v;
            v.x = lrelu1(acc3[j]);     v.y = lrelu1(acc3[j + 1]);
            v.z = lrelu1(acc3[j + 2]); v.w = lrelu1(acc3[j + 3]);
            *(float4*)&hrow[j] = v;
        }
#pragma unroll
        for (int j = 0; j < 32; ++j) acc3[j] = mb2[j];
        gemm_block(mw2, hrow, acc3);
#pragma unroll
        for (int j = 0; j < 32; j += 4) {
            float4 v;
            v.x = lrelu1(acc3[j]);     v.y = lrelu1(acc3[j + 1]);
            v.z = lrelu1(acc3[j + 2]); v.w = lrelu1(acc3[j + 3]);
            *(float4*)&hrow[j] = v;
        }
#pragma unroll
        for (int j = 0; j < 32; ++j) acc3[j] = mb3[j];
        gemm_block(mw3, hrow, acc3);
        if (e < E) {
#pragma unroll
            for (int j = 0; j < 32; j += 4)
                *(float4*)(mout + (size_t)e * 32 + j) =
                    make_float4(acc3[j], acc3[j + 1], acc3[j + 2], acc3[j + 3]);
        }
    }
}

// ---------------- CSR scatter-mean (gather form) ----------------
__global__ __launch_bounds__(256)
void mean_kernel(const float* __restrict__ esrc, const int* __restrict__ off,
                 const int* __restrict__ perm, float* __restrict__ nout, int N)
{
    const int t = threadIdx.x;
    const int n = blockIdx.x * 32 + (t >> 3);
    if (n >= N) return;
    const int cg = t & 7;
    const int o0 = off[n], o1 = off[n + 1];
    float4 acc = make_float4(0.f, 0.f, 0.f, 0.f);
    for (int i = o0; i < o1; ++i) {
        int e = perm[i];
        float4 v = *(const float4*)(esrc + (size_t)e * 32 + cg * 4);
        acc.x += invlrelu1(v.x); acc.y += invlrelu1(v.y);
        acc.z += invlrelu1(v.z); acc.w += invlrelu1(v.w);
    }
    float inv = 1.0f / (float)max(o1 - o0, 1);
    float4 r;
    r.x = lrelu1(acc.x * inv); r.y = lrelu1(acc.y * inv);
    r.z = lrelu1(acc.z * inv); r.w = lrelu1(acc.w * inv);
    *(float4*)(nout + (size_t)n * 32 + cg * 4) = r;
}

// ---------------- 3-layer 32->32 MLP (lrelu, lrelu, none) ----------------
__global__ __launch_bounds__(256, 4)
void mlp3_kernel(const float* __restrict__ in,
                 const float* __restrict__ w1g, const float* __restrict__ b1g,
                 const float* __restrict__ w2g, const float* __restrict__ b2g,
                 const float* __restrict__ w3g, const float* __restrict__ b3g,
                 float* __restrict__ out, int M)
{
    __shared__ float hs[256 * PADF];
    const int tid = threadIdx.x;
    const int base = blockIdx.x * 256;
    const int se = tid >> 3, sq = tid & 7;
    float* hrow = hs + tid * PADF;

    float4 stg[8];
    stage_load(in, stg, base, se, sq, M);
    stage_write(stg, hs, se, sq);
    __syncthreads();

    float acc[32];
#pragma unroll
    for (int j = 0; j < 32; ++j) acc[j] = b1g[j];
    gemm_block(w1g, hrow, acc);
#pragma unroll
    for (int j = 0; j < 32; j += 4) {
        float4 v;
        v.x = lrelu1(acc[j]);     v.y = lrelu1(acc[j + 1]);
        v.z = lrelu1(acc[j + 2]); v.w = lrelu1(acc[j + 3]);
        *(float4*)&hrow[j] = v;
    }
#pragma unroll
    for (int j = 0; j < 32; ++j) acc[j] = b2g[j];
    gemm_block(w2g, hrow, acc);
#pragma unroll
    for (int j = 0; j < 32; j += 4) {
        float4 v;
        v.x = lrelu1(acc[j]);     v.y = lrelu1(acc[j + 1]);
        v.z = lrelu1(acc[j + 2]); v.w = lrelu1(acc[j + 3]);
        *(float4*)&hrow[j] = v;
    }
#pragma unroll
    for (int j = 0; j < 32; ++j) acc[j] = b3g[j];
    gemm_block(w3g, hrow, acc);

    int m = base + tid;
    if (m < M) {
#pragma unroll
        for (int j = 0; j < 32; j += 4)
            *(float4*)(out + (size_t)m * 32 + j) =
                make_float4(acc[j], acc[j + 1], acc[j + 2], acc[j + 3]);
    }
}

extern "C" void kernel_launch(void* const* d_in, const int* in_sizes, int n_in,
                              void* d_out, int out_size, void* d_ws, size_t ws_size,
                              hipStream_t stream)
{
    const float* node_attr = (const float*)d_in[0];
    const float* edge_attr = (const float*)d_in[1];
    const int*   eidx      = (const int*)d_in[2];
    const float* c1w1 = (const float*)d_in[3];  const float* c1b1 = (const float*)d_in[4];
    const float* c1w2 = (const float*)d_in[5];  const float* c1b2 = (const float*)d_in[6];
    const float* c2w1 = (const float*)d_in[7];  const float* c2b1 = (const float*)d_in[8];
    const float* c2w2 = (const float*)d_in[9];  const float* c2b2 = (const float*)d_in[10];
    const float* c3w1 = (const float*)d_in[11]; const float* c3b1 = (const float*)d_in[12];
    const float* c3w2 = (const float*)d_in[13]; const float* c3b2 = (const float*)d_in[14];
    const float* nw1  = (const float*)d_in[15]; const float* nb1  = (const float*)d_in[16];
    const float* nw2  = (const float*)d_in[17]; const float* nb2  = (const float*)d_in[18];
    const float* nw3  = (const float*)d_in[19]; const float* nb3  = (const float*)d_in[20];
    const float* ew1  = (const float*)d_in[21]; const float* eb1  = (const float*)d_in[22];
    const float* ew2  = (const float*)d_in[23]; const float* eb2  = (const float*)d_in[24];
    const float* ew3  = (const float*)d_in[25]; const float* eb3  = (const float*)d_in[26];

    const int N = in_sizes[0] / 32;
    const int E = in_sizes[1] / 32;
    const int* rowi = eidx;
    const int* coli = eidx + E;

    float* out      = (float*)d_out;
    float* node_out = out;                       // N*32
    float* edge_out = out + (size_t)N * 32;      // E*32

    // workspace: ints first, then 256B-aligned floats
    int* deg    = (int*)d_ws;                    // N
    int* off    = deg + N;                       // N+1
    int* cursor = off + (N + 1);                 // N
    int* perm   = cursor + N;                    // E
    uintptr_t a = ((uintptr_t)(perm + E) + 255) & ~(uintptr_t)255;
    float* n1 = (float*)a;                       // 32N (doubles as Pr/Pc buffer)
    float* n2 = n1 + (size_t)32 * N;             // 32N (doubles as Pr/Pc buffer)
    float* e1 = n2 + (size_t)32 * N;             // 32E (doubles as e3 scratch)
    float* e2 = e1 + (size_t)32 * E;             // 32E

    const int gridE   = (E + 255) / 256;
    const int gridN32 = (N + 31) / 32;
    const int gridN   = (N + 255) / 256;

    // ---- CSR build (once, reused by all 3 convs) ----
    hipMemsetAsync(deg, 0, (size_t)N * sizeof(int), stream);
    hist_kernel<<<gridE, 256, 0, stream>>>(rowi, deg, E);
    scan_kernel<<<1, 256, 0, stream>>>(deg, off, cursor, N, E);
    place_kernel<<<gridE, 256, 0, stream>>>(rowi, cursor, perm, E);

    // ---- conv1: Pr1=n1, Pc1=n2 ----
    pre_kernel<<<gridN, 256, 0, stream>>>(node_attr, c1w1, c1b1, n1, n2, N);
    conv_kernel<1, false><<<gridE, 256, 0, stream>>>(
        n1, n2, rowi, coli, edge_attr, nullptr, nullptr,
        c1w1 + 2048, c1w2, c1b2, e1,
        nullptr, nullptr, nullptr, nullptr, nullptr, nullptr, nullptr, E);
    mean_kernel<<<gridN32, 256, 0, stream>>>(e1, off, perm, n1, N);   // n1 <- node state 1

    // ---- conv2: Pr2=n1 (in-place over n1), Pc2=n2 ----
    pre_kernel<<<gridN, 256, 0, stream>>>(n1, c2w1, c2b1, n1, n2, N);
    conv_kernel<2, false><<<gridE, 256, 0, stream>>>(
        n1, n2, rowi, coli, e1, edge_attr, nullptr,
        c2w1 + 2048, c2w2, c2b2, e2,
        nullptr, nullptr, nullptr, nullptr, nullptr, nullptr, nullptr, E);
    mean_kernel<<<gridN32, 256, 0, stream>>>(e2, off, perm, n2, N);   // n2 <- node state 2

    // ---- conv3 (fused edge MLP): Pr3=n2 (in-place), Pc3=n1; e3 -> e1 (block-local RAW-safe) ----
    pre_kernel<<<gridN, 256, 0, stream>>>(n2, c3w1, c3b1, n2, n1, N);
    conv_kernel<3, true><<<gridE, 256, 0, stream>>>(
        n2, n1, rowi, coli, e2, e1, edge_attr,
        c3w1 + 2048, c3w2, c3b2, /*e3 scratch*/ e1,
        ew1, eb1, ew2, eb2, ew3, eb3, /*final*/ edge_out, E);
    mean_kernel<<<gridN32, 256, 0, stream>>>(e1, off, perm, n1, N);   // n1 <- n3

    // ---- node output MLP ----
    mlp3_kernel<<<gridN, 256, 0, stream>>>(n1, nw1, nb1, nw2, nb2, nw3, nb3,
                                           node_out, N);
}

// Round 3
// 1654.866 us; speedup vs baseline: 1.1184x; 1.1184x over previous
//
#include <hip/hip_runtime.h>

#define DEVINL __device__ __forceinline__

constexpr int PADF = 36;   // LDS row stride in floats (144B: 16B-aligned, breaks 32-bank alias)

DEVINL float lrelu1(float v)    { return v > 0.f ? v : 0.2f * v; }
DEVINL float invlrelu1(float v) { return v > 0.f ? v : 5.0f * v; }

// acc[32] += hrow(32 floats, own LDS row) @ wg[32][32] (global, wave-uniform -> s_load)
// kq outer (unroll 1, small code), 128 FMAs per h-read; h prefetched one iter ahead.
DEVINL void gemm_block(const float* __restrict__ wg, const float* hrow, float acc[32])
{
    float4 h = *(const float4*)(hrow);
#pragma unroll 1
    for (int kq = 0; kq < 8; ++kq) {
        float4 hn = *(const float4*)(hrow + ((kq + 1) & 7) * 4);   // prefetch next quad
#pragma unroll
        for (int i = 0; i < 4; ++i) {
            float hv = ((const float*)&h)[i];
            const float* wr = wg + (kq * 4 + i) * 32;
#pragma unroll
            for (int j = 0; j < 32; j += 4) {
                float4 w = *(const float4*)(wr + j);
                acc[j + 0] = fmaf(hv, w.x, acc[j + 0]);
                acc[j + 1] = fmaf(hv, w.y, acc[j + 1]);
                acc[j + 2] = fmaf(hv, w.z, acc[j + 2]);
                acc[j + 3] = fmaf(hv, w.w, acc[j + 3]);
            }
        }
        h = hn;
    }
}

// cooperative staging of 256 contiguous rows (32 floats each) into LDS
// short live ranges: each float4 goes global->reg->LDS immediately (no spill pressure)
DEVINL void stage_rows(const float* __restrict__ src, float* __restrict__ hs,
                       int base, int se, int sq, int limit)
{
#pragma unroll
    for (int p = 0; p < 8; ++p) {
        int lr = p * 32 + se;
        int m = base + lr; if (m >= limit) m = limit - 1;
        float4 v = *(const float4*)(src + (size_t)m * 32 + sq * 4);
        *(float4*)&hs[lr * PADF + sq * 4] = v;
    }
}

// ---------------- CSR build ----------------
__global__ __launch_bounds__(256)
void hist_kernel(const int* __restrict__ rowi, int* __restrict__ deg, int E)
{
    int e = blockIdx.x * 256 + threadIdx.x;
    if (e < E) atomicAdd(&deg[rowi[e]], 1);
}

__global__ __launch_bounds__(256)
void scan_kernel(const int* __restrict__ deg, int* __restrict__ off,
                 int* __restrict__ cursor, int N, int E)
{
    __shared__ int part[256];
    __shared__ int psum[256];
    const int t = threadIdx.x;
    const int per = (N + 255) / 256;
    const int b0 = t * per;
    int s = 0;
    for (int i = 0; i < per; ++i) { int idx = b0 + i; if (idx < N) s += deg[idx]; }
    part[t] = s;
    __syncthreads();
    if (t == 0) { int run = 0; for (int i = 0; i < 256; ++i) { psum[i] = run; run += part[i]; } }
    __syncthreads();
    int run = psum[t];
    for (int i = 0; i < per; ++i) {
        int idx = b0 + i;
        if (idx < N) { off[idx] = run; cursor[idx] = run; run += deg[idx]; }
    }
    if (t == 0) off[N] = E;
}

__global__ __launch_bounds__(256)
void place_kernel(const int* __restrict__ rowi, int* __restrict__ cursor,
                  int* __restrict__ perm, int E)
{
    int e = blockIdx.x * 256 + threadIdx.x;
    if (e < E) {
        int r = rowi[e];
        int p = atomicAdd(&cursor[r], 1);
        perm[p] = e;
    }
}

// ---------------- per-node precompute: Pr = x@w1[0:32] + b1, Pc = x@w1[32:64] ----------------
// safe in-place (block reads its rows before writing them; cross-block rows disjoint)
__global__ __launch_bounds__(256, 4)
void pre_kernel(const float* __restrict__ x, const float* __restrict__ w1,
                const float* __restrict__ b1,
                float* __restrict__ Pr, float* __restrict__ Pc, int N)
{
    __shared__ float hs[256 * PADF];
    const int tid = threadIdx.x;
    const int base = blockIdx.x * 256;
    const int se = tid >> 3, sq = tid & 7;
    const float* hrow = hs + tid * PADF;

    stage_rows(x, hs, base, se, sq, N);
    __syncthreads();

    const int n = base + tid;
    float acc[32];
#pragma unroll
    for (int j = 0; j < 32; ++j) acc[j] = b1[j];
    gemm_block(w1, hrow, acc);
    if (n < N) {
#pragma unroll
        for (int j = 0; j < 32; j += 4)
            *(float4*)(Pr + (size_t)n * 32 + j) = make_float4(acc[j], acc[j+1], acc[j+2], acc[j+3]);
    }
#pragma unroll
    for (int j = 0; j < 32; ++j) acc[j] = 0.f;
    gemm_block(w1 + 1024, hrow, acc);
    if (n < N) {
#pragma unroll
        for (int j = 0; j < 32; j += 4)
            *(float4*)(Pc + (size_t)n * 32 + j) = make_float4(acc[j], acc[j+1], acc[j+2], acc[j+3]);
    }
}

// ---------------- edge conv ----------------
// acc = Pr[row] + Pc[col] (+ staged edge-feature chunks @ w1e) ; relu ; @w2+b2 ; lrelu
// FUSE: additionally run the 3-layer edge MLP in the same pass
template<int NCHUNK, bool FUSE>
__global__ __launch_bounds__(256, 4)
void conv_kernel(const float* __restrict__ Pr, const float* __restrict__ Pc,
                 const int* __restrict__ rowi, const int* __restrict__ coli,
                 const float* __restrict__ f0, const float* __restrict__ f1,
                 const float* __restrict__ f2,
                 const float* __restrict__ w1e,
                 const float* __restrict__ w2g, const float* __restrict__ b2g,
                 float* __restrict__ eout,
                 const float* __restrict__ mw1, const float* __restrict__ mb1,
                 const float* __restrict__ mw2, const float* __restrict__ mb2,
                 const float* __restrict__ mw3, const float* __restrict__ mb3,
                 float* __restrict__ mout,
                 int E)
{
    __shared__ float hs[256 * PADF];
    const int tid = threadIdx.x;
    const int base = blockIdx.x * 256;
    const int se = tid >> 3, sq = tid & 7;
    float* hrow = hs + tid * PADF;

    // chunk-0 staging loads + Pr/Pc gathers all issued up front
    stage_rows(f0, hs, base, se, sq, E);

    const int e = base + tid;
    const int ee = e < E ? e : E - 1;
    const int r = rowi[ee], c = coli[ee];
    const float* pr = Pr + (size_t)r * 32;
    const float* pc = Pc + (size_t)c * 32;
    float acc[32];
#pragma unroll
    for (int q = 0; q < 8; ++q) {
        float4 ga = *(const float4*)(pr + q * 4);
        float4 gb = *(const float4*)(pc + q * 4);
        acc[q * 4 + 0] = ga.x + gb.x;
        acc[q * 4 + 1] = ga.y + gb.y;
        acc[q * 4 + 2] = ga.z + gb.z;
        acc[q * 4 + 3] = ga.w + gb.w;
    }
    __syncthreads();
    gemm_block(w1e, hrow, acc);

#pragma unroll
    for (int cch = 1; cch < NCHUNK; ++cch) {
        const float* src = (cch == 1) ? f1 : f2;
        __syncthreads();                       // prev gemm's hrow reads done everywhere
        stage_rows(src, hs, base, se, sq, E);
        __syncthreads();
        gemm_block(w1e + cch * 1024, hrow, acc);
    }

    // relu -> own LDS row (no barrier: only own-row access from here on)
#pragma unroll
    for (int j = 0; j < 32; j += 4) {
        float4 v;
        v.x = fmaxf(acc[j],     0.f); v.y = fmaxf(acc[j + 1], 0.f);
        v.z = fmaxf(acc[j + 2], 0.f); v.w = fmaxf(acc[j + 3], 0.f);
        *(float4*)&hrow[j] = v;
    }
    float acc2[32];
#pragma unroll
    for (int j = 0; j < 32; ++j) acc2[j] = b2g[j];
    gemm_block(w2g, hrow, acc2);

    if constexpr (!FUSE) {
        if (e < E) {
#pragma unroll
            for (int j = 0; j < 32; j += 4) {
                float4 v;
                v.x = lrelu1(acc2[j]);     v.y = lrelu1(acc2[j + 1]);
                v.z = lrelu1(acc2[j + 2]); v.w = lrelu1(acc2[j + 3]);
                *(float4*)(eout + (size_t)e * 32 + j) = v;
            }
        }
    } else {
        // e3 = lrelu(acc2) -> scratch (for scatter-mean) + own row (MLP input)
#pragma unroll
        for (int j = 0; j < 32; j += 4) {
            float4 v;
            v.x = lrelu1(acc2[j]);     v.y = lrelu1(acc2[j + 1]);
            v.z = lrelu1(acc2[j + 2]); v.w = lrelu1(acc2[j + 3]);
            *(float4*)&hrow[j] = v;
            if (e < E) *(float4*)(eout + (size_t)e * 32 + j) = v;
        }
        float acc3[32];
#pragma unroll
        for (int j = 0; j < 32; ++j) acc3[j] = mb1[j];
        gemm_block(mw1, hrow, acc3);
#pragma unroll
        for (int j = 0; j < 32; j += 4) {
            float4 v;
            v.x = lrelu1(acc3[j]);     v.y = lrelu1(acc3[j + 1]);
            v.z = lrelu1(acc3[j + 2]); v.w = lrelu1(acc3[j + 3]);
            *(float4*)&hrow[j] = v;
        }
#pragma unroll
        for (int j = 0; j < 32; ++j) acc3[j] = mb2[j];
        gemm_block(mw2, hrow, acc3);
#pragma unroll
        for (int j = 0; j < 32; j += 4) {
            float4 v;
            v.x = lrelu1(acc3[j]);     v.y = lrelu1(acc3[j + 1]);
            v.z = lrelu1(acc3[j + 2]); v.w = lrelu1(acc3[j + 3]);
            *(float4*)&hrow[j] = v;
        }
#pragma unroll
        for (int j = 0; j < 32; ++j) acc3[j] = mb3[j];
        gemm_block(mw3, hrow, acc3);
        if (e < E) {
#pragma unroll
            for (int j = 0; j < 32; j += 4)
                *(float4*)(mout + (size_t)e * 32 + j) =
                    make_float4(acc3[j], acc3[j + 1], acc3[j + 2], acc3[j + 3]);
        }
    }
}

// ---------------- CSR scatter-mean (gather form) ----------------
__global__ __launch_bounds__(256)
void mean_kernel(const float* __restrict__ esrc, const int* __restrict__ off,
                 const int* __restrict__ perm, float* __restrict__ nout, int N)
{
    const int t = threadIdx.x;
    const int n = blockIdx.x * 32 + (t >> 3);
    if (n >= N) return;
    const int cg = t & 7;
    const int o0 = off[n], o1 = off[n + 1];
    float4 acc = make_float4(0.f, 0.f, 0.f, 0.f);
    for (int i = o0; i < o1; ++i) {
        int e = perm[i];
        float4 v = *(const float4*)(esrc + (size_t)e * 32 + cg * 4);
        acc.x += invlrelu1(v.x); acc.y += invlrelu1(v.y);
        acc.z += invlrelu1(v.z); acc.w += invlrelu1(v.w);
    }
    float inv = 1.0f / (float)max(o1 - o0, 1);
    float4 r;
    r.x = lrelu1(acc.x * inv); r.y = lrelu1(acc.y * inv);
    r.z = lrelu1(acc.z * inv); r.w = lrelu1(acc.w * inv);
    *(float4*)(nout + (size_t)n * 32 + cg * 4) = r;
}

// ---------------- 3-layer 32->32 MLP (lrelu, lrelu, none) ----------------
__global__ __launch_bounds__(256, 4)
void mlp3_kernel(const float* __restrict__ in,
                 const float* __restrict__ w1g, const float* __restrict__ b1g,
                 const float* __restrict__ w2g, const float* __restrict__ b2g,
                 const float* __restrict__ w3g, const float* __restrict__ b3g,
                 float* __restrict__ out, int M)
{
    __shared__ float hs[256 * PADF];
    const int tid = threadIdx.x;
    const int base = blockIdx.x * 256;
    const int se = tid >> 3, sq = tid & 7;
    float* hrow = hs + tid * PADF;

    stage_rows(in, hs, base, se, sq, M);
    __syncthreads();

    float acc[32];
#pragma unroll
    for (int j = 0; j < 32; ++j) acc[j] = b1g[j];
    gemm_block(w1g, hrow, acc);
#pragma unroll
    for (int j = 0; j < 32; j += 4) {
        float4 v;
        v.x = lrelu1(acc[j]);     v.y = lrelu1(acc[j + 1]);
        v.z = lrelu1(acc[j + 2]); v.w = lrelu1(acc[j + 3]);
        *(float4*)&hrow[j] = v;
    }
#pragma unroll
    for (int j = 0; j < 32; ++j) acc[j] = b2g[j];
    gemm_block(w2g, hrow, acc);
#pragma unroll
    for (int j = 0; j < 32; j += 4) {
        float4 v;
        v.x = lrelu1(acc[j]);     v.y = lrelu1(acc[j + 1]);
        v.z = lrelu1(acc[j + 2]); v.w = lrelu1(acc[j + 3]);
        *(float4*)&hrow[j] = v;
    }
#pragma unroll
    for (int j = 0; j < 32; ++j) acc[j] = b3g[j];
    gemm_block(w3g, hrow, acc);

    int m = base + tid;
    if (m < M) {
#pragma unroll
        for (int j = 0; j < 32; j += 4)
            *(float4*)(out + (size_t)m * 32 + j) =
                make_float4(acc[j], acc[j + 1], acc[j + 2], acc[j + 3]);
    }
}

extern "C" void kernel_launch(void* const* d_in, const int* in_sizes, int n_in,
                              void* d_out, int out_size, void* d_ws, size_t ws_size,
                              hipStream_t stream)
{
    const float* node_attr = (const float*)d_in[0];
    const float* edge_attr = (const float*)d_in[1];
    const int*   eidx      = (const int*)d_in[2];
    const float* c1w1 = (const float*)d_in[3];  const float* c1b1 = (const float*)d_in[4];
    const float* c1w2 = (const float*)d_in[5];  const float* c1b2 = (const float*)d_in[6];
    const float* c2w1 = (const float*)d_in[7];  const float* c2b1 = (const float*)d_in[8];
    const float* c2w2 = (const float*)d_in[9];  const float* c2b2 = (const float*)d_in[10];
    const float* c3w1 = (const float*)d_in[11]; const float* c3b1 = (const float*)d_in[12];
    const float* c3w2 = (const float*)d_in[13]; const float* c3b2 = (const float*)d_in[14];
    const float* nw1  = (const float*)d_in[15]; const float* nb1  = (const float*)d_in[16];
    const float* nw2  = (const float*)d_in[17]; const float* nb2  = (const float*)d_in[18];
    const float* nw3  = (const float*)d_in[19]; const float* nb3  = (const float*)d_in[20];
    const float* ew1  = (const float*)d_in[21]; const float* eb1  = (const float*)d_in[22];
    const float* ew2  = (const float*)d_in[23]; const float* eb2  = (const float*)d_in[24];
    const float* ew3  = (const float*)d_in[25]; const float* eb3  = (const float*)d_in[26];

    const int N = in_sizes[0] / 32;
    const int E = in_sizes[1] / 32;
    const int* rowi = eidx;
    const int* coli = eidx + E;

    float* out      = (float*)d_out;
    float* node_out = out;                       // N*32
    float* edge_out = out + (size_t)N * 32;      // E*32

    // workspace: ints first, then 256B-aligned floats
    int* deg    = (int*)d_ws;                    // N
    int* off    = deg + N;                       // N+1
    int* cursor = off + (N + 1);                 // N
    int* perm   = cursor + N;                    // E
    uintptr_t a = ((uintptr_t)(perm + E) + 255) & ~(uintptr_t)255;
    float* n1 = (float*)a;                       // 32N (doubles as Pr/Pc buffer)
    float* n2 = n1 + (size_t)32 * N;             // 32N (doubles as Pr/Pc buffer)
    float* e1 = n2 + (size_t)32 * N;             // 32E (doubles as e3 scratch)
    float* e2 = e1 + (size_t)32 * E;             // 32E

    const int gridE   = (E + 255) / 256;
    const int gridN32 = (N + 31) / 32;
    const int gridN   = (N + 255) / 256;

    // ---- CSR build (once, reused by all 3 convs) ----
    hipMemsetAsync(deg, 0, (size_t)N * sizeof(int), stream);
    hist_kernel<<<gridE, 256, 0, stream>>>(rowi, deg, E);
    scan_kernel<<<1, 256, 0, stream>>>(deg, off, cursor, N, E);
    place_kernel<<<gridE, 256, 0, stream>>>(rowi, cursor, perm, E);

    // ---- conv1: Pr1=n1, Pc1=n2 ----
    pre_kernel<<<gridN, 256, 0, stream>>>(node_attr, c1w1, c1b1, n1, n2, N);
    conv_kernel<1, false><<<gridE, 256, 0, stream>>>(
        n1, n2, rowi, coli, edge_attr, nullptr, nullptr,
        c1w1 + 2048, c1w2, c1b2, e1,
        nullptr, nullptr, nullptr, nullptr, nullptr, nullptr, nullptr, E);
    mean_kernel<<<gridN32, 256, 0, stream>>>(e1, off, perm, n1, N);   // n1 <- node state 1

    // ---- conv2: Pr2=n1 (in-place over n1), Pc2=n2 ----
    pre_kernel<<<gridN, 256, 0, stream>>>(n1, c2w1, c2b1, n1, n2, N);
    conv_kernel<2, false><<<gridE, 256, 0, stream>>>(
        n1, n2, rowi, coli, e1, edge_attr, nullptr,
        c2w1 + 2048, c2w2, c2b2, e2,
        nullptr, nullptr, nullptr, nullptr, nullptr, nullptr, nullptr, E);
    mean_kernel<<<gridN32, 256, 0, stream>>>(e2, off, perm, n2, N);   // n2 <- node state 2

    // ---- conv3 (fused edge MLP): Pr3=n2 (in-place), Pc3=n1; e3 -> e1 (block-local RAW-safe) ----
    pre_kernel<<<gridN, 256, 0, stream>>>(n2, c3w1, c3b1, n2, n1, N);
    conv_kernel<3, true><<<gridE, 256, 0, stream>>>(
        n2, n1, rowi, coli, e2, e1, edge_attr,
        c3w1 + 2048, c3w2, c3b2, /*e3 scratch*/ e1,
        ew1, eb1, ew2, eb2, ew3, eb3, /*final*/ edge_out, E);
    mean_kernel<<<gridN32, 256, 0, stream>>>(e1, off, perm, n1, N);   // n1 <- n3

    // ---- node output MLP ----
    mlp3_kernel<<<gridN, 256, 0, stream>>>(n1, nw1, nb1, nw2, nb2, nw3, nb3,
                                           node_out, N);
}